// Round 2
// baseline (254.781 us; speedup 1.0000x reference)
//
#include <hip/hip_runtime.h>

#define GLD16(gp, lp) __builtin_amdgcn_global_load_lds( \
    (const __attribute__((address_space(1))) void*)(gp), \
    (__attribute__((address_space(3))) void*)(lp), 16, 0, 0)

typedef __attribute__((ext_vector_type(8))) short bf16x8;
typedef __attribute__((ext_vector_type(4))) float f32x4;

__device__ __forceinline__ short f2bf(float f) {
    union { float f; unsigned u; } x; x.f = f;
    unsigned r = x.u + 0x7fffu + ((x.u >> 16) & 1u);
    return (short)(r >> 16);
}
__device__ __forceinline__ float bf2f(short s) {
    union { unsigned u; float f; } x;
    x.u = ((unsigned)(unsigned short)s) << 16;
    return x.f;
}

// ---------------- K0: weights fp32 -> bf16 ----------------
__global__ __launch_bounds__(256) void cvt_weights(
    const float* __restrict__ qkv_w, const float* __restrict__ proj_w,
    short* __restrict__ wq, short* __restrict__ wp)
{
    int idx = blockIdx.x * 256 + threadIdx.x;   // 262144 float4s total
    const int NQ4 = (1536 * 512) / 4;           // 196608
    float4 f; short4 s;
    if (idx < NQ4) {
        f = ((const float4*)qkv_w)[idx];
        s.x = f2bf(f.x); s.y = f2bf(f.y); s.z = f2bf(f.z); s.w = f2bf(f.w);
        ((short4*)wq)[idx] = s;
    } else {
        int j = idx - NQ4;                      // 65536 for proj
        f = ((const float4*)proj_w)[j];
        s.x = f2bf(f.x); s.y = f2bf(f.y); s.z = f2bf(f.z); s.w = f2bf(f.w);
        ((short4*)wp)[j] = s;
    }
}

// ---------------- K1: groupnorm stats ----------------
// one block per (b,g); group = 16 ch x 1024 spatial = 16384 contiguous floats
__global__ __launch_bounds__(256) void gn_stats(
    const float* __restrict__ x, float* __restrict__ mean, float* __restrict__ rstd)
{
    int bg = blockIdx.x;  // 0..511
    const float4* p = (const float4*)(x + (size_t)bg * 16384);
    float s = 0.f, ss = 0.f;
    for (int i = threadIdx.x; i < 4096; i += 256) {
        float4 v = p[i];
        s  += v.x + v.y + v.z + v.w;
        ss += v.x * v.x + v.y * v.y + v.z * v.z + v.w * v.w;
    }
    #pragma unroll
    for (int o = 32; o > 0; o >>= 1) {
        s  += __shfl_down(s, o);
        ss += __shfl_down(ss, o);
    }
    __shared__ float ls[4], lss[4];
    int wave = threadIdx.x >> 6;
    if ((threadIdx.x & 63) == 0) { ls[wave] = s; lss[wave] = ss; }
    __syncthreads();
    if (threadIdx.x == 0) {
        s  = ls[0] + ls[1] + ls[2] + ls[3];
        ss = lss[0] + lss[1] + lss[2] + lss[3];
        float m = s * (1.f / 16384.f);
        float var = ss * (1.f / 16384.f) - m * m;
        mean[bg] = m;
        rstd[bg] = rsqrtf(var + 1e-5f);
    }
}

// ---------------- K2: normalize + transpose -> xnT [B,HW,C] bf16 ----------------
__global__ __launch_bounds__(256) void gn_apply_t(
    const float* __restrict__ x, const float* __restrict__ w, const float* __restrict__ bb,
    const float* __restrict__ mean, const float* __restrict__ rstd,
    short* __restrict__ xnT)
{
    __shared__ short tile[64][65];
    int b = blockIdx.z, cblk = blockIdx.y, nblk = blockIdx.x;
    int t = threadIdx.x;
    int nl = t & 63;
    int cb = t >> 6;  // 0..3
    #pragma unroll
    for (int i = 0; i < 16; ++i) {
        int cl = cb * 16 + i;
        int cg = cblk * 64 + cl;
        int bgid = b * 32 + (cg >> 4);
        float sc = rstd[bgid] * w[cg];
        float sh = bb[cg] - mean[bgid] * sc;
        float xv = x[((size_t)(b * 512 + cg)) * 1024 + nblk * 64 + nl];
        tile[cl][nl] = f2bf(xv * sc + sh);
    }
    __syncthreads();
    int ng = t >> 4;            // 0..15
    int c4 = (t & 15) * 4;
    #pragma unroll
    for (int p = 0; p < 4; ++p) {
        int nl2 = p * 16 + ng;
        short4 sv;
        sv.x = tile[c4 + 0][nl2];
        sv.y = tile[c4 + 1][nl2];
        sv.z = tile[c4 + 2][nl2];
        sv.w = tile[c4 + 3][nl2];
        *(short4*)&xnT[((size_t)(b * 1024 + nblk * 64 + nl2)) * 512 + cblk * 64 + c4] = sv;
    }
}

// ---------------- shared NT-GEMM core: 128x128 tile, BK=32, 4 waves ----------------
// A: [M][K] row-major bf16 (block's 128 rows at A), B: [N][K] row-major bf16.
// acc[m][n] frag rows = M-dim, cols = N-dim.
__device__ __forceinline__ void gemm_nt_core(
    const short* __restrict__ A, const short* __restrict__ B,
    const int K, const int lda, const int ldb,
    short* lA, short* lB, f32x4 acc[4][4])
{
    const int t    = threadIdx.x;
    const int lane = t & 63;
    const int wave = t >> 6;
    const int wm = (wave >> 1) * 64;
    const int wn = (wave & 1) * 64;
    const int fr = lane & 15;
    const int fk = lane >> 4;
    const int arow = t >> 2;          // 0..63
    const int acol = (t & 3) * 8;     // 0,8,16,24

    const short* pa = A + (size_t)arow * lda + acol;
    const short* pb = B + (size_t)arow * ldb + acol;
    short* la_dst = lA + t * 8;
    short* lb_dst = lB + t * 8;
    const size_t astep = (size_t)64 * lda;
    const size_t bstep = (size_t)64 * ldb;

    for (int k0 = 0; k0 < K; k0 += 32) {
        GLD16(pa + k0,         la_dst);
        GLD16(pa + k0 + astep, la_dst + 2048);
        GLD16(pb + k0,         lb_dst);
        GLD16(pb + k0 + bstep, lb_dst + 2048);
        __syncthreads();
        bf16x8 af[4], bfr[4];
        #pragma unroll
        for (int m = 0; m < 4; ++m)
            af[m] = *(const bf16x8*)&lA[(wm + m * 16 + fr) * 32 + fk * 8];
        #pragma unroll
        for (int n = 0; n < 4; ++n)
            bfr[n] = *(const bf16x8*)&lB[(wn + n * 16 + fr) * 32 + fk * 8];
        #pragma unroll
        for (int m = 0; m < 4; ++m)
            #pragma unroll
            for (int n = 0; n < 4; ++n)
                acc[m][n] = __builtin_amdgcn_mfma_f32_16x16x32_bf16(af[m], bfr[n], acc[m][n], 0, 0, 0);
        __syncthreads();
    }
}

// ---------------- K3: QKV GEMM ----------------
// out[o,n] = sum_c wq[o,c]*xnT[b,n,c];  o<512 -> qT (scaled), <1024 -> kT, else v
__global__ __launch_bounds__(256) void qkv_gemm(
    const short* __restrict__ wq, const float* __restrict__ qkv_b,
    const short* __restrict__ xnT,
    short* __restrict__ qT, short* __restrict__ kT, short* __restrict__ vv)
{
    __shared__ short lA[128 * 32], lB[128 * 32];
    const int b  = blockIdx.z;
    const int bm = blockIdx.y;   // 0..11 over 1536 rows
    const int bn = blockIdx.x;   // 0..7 over 1024 cols
    const short* A = wq + (size_t)bm * 128 * 512;
    const short* B = xnT + ((size_t)b * 1024 + bn * 128) * 512;
    f32x4 acc[4][4] = {};
    gemm_nt_core(A, B, 512, 512, 512, lA, lB, acc);

    const int lane = threadIdx.x & 63;
    const int wave = threadIdx.x >> 6;
    const int wm = (wave >> 1) * 64;
    const int wn = (wave & 1) * 64;
    const int fr = lane & 15;
    const int fk = lane >> 4;
    const int region = bm >> 2;  // 0=q 1=k 2=v
    const float qscale = 0.04419417382415922f;  // 1/sqrt(512)

    #pragma unroll
    for (int m = 0; m < 4; ++m) {
        int o0 = bm * 128 + wm + m * 16 + fk * 4;
        float4 bias = *(const float4*)&qkv_b[o0];
        #pragma unroll
        for (int n = 0; n < 4; ++n) {
            int col = bn * 128 + wn + n * 16 + fr;
            f32x4 a = acc[m][n];
            if (region == 0) {
                short4 sv;
                sv.x = f2bf((a[0] + bias.x) * qscale);
                sv.y = f2bf((a[1] + bias.y) * qscale);
                sv.z = f2bf((a[2] + bias.z) * qscale);
                sv.w = f2bf((a[3] + bias.w) * qscale);
                *(short4*)&qT[((size_t)(b * 1024 + col)) * 512 + o0] = sv;
            } else if (region == 1) {
                short4 sv;
                sv.x = f2bf(a[0] + bias.x);
                sv.y = f2bf(a[1] + bias.y);
                sv.z = f2bf(a[2] + bias.z);
                sv.w = f2bf(a[3] + bias.w);
                *(short4*)&kT[((size_t)(b * 1024 + col)) * 512 + (o0 - 512)] = sv;
            } else {
                float bb4[4] = {bias.x, bias.y, bias.z, bias.w};
                #pragma unroll
                for (int r = 0; r < 4; ++r)
                    vv[((size_t)(b * 512 + (o0 - 1024 + r))) * 1024 + col] = f2bf(a[r] + bb4[r]);
            }
        }
    }
}

// ---------------- K4: S = q.kT (A=kT rows m, B=qT rows n) -> S[b,n,m] bf16 ----------------
__global__ __launch_bounds__(256) void s_gemm(
    const short* __restrict__ kT, const short* __restrict__ qT, short* __restrict__ S)
{
    __shared__ short lA[128 * 32], lB[128 * 32];
    const int b  = blockIdx.z;
    const int bm = blockIdx.y;   // m tiles
    const int bn = blockIdx.x;   // n tiles
    const short* A = kT + ((size_t)b * 1024 + bm * 128) * 512;
    const short* B = qT + ((size_t)b * 1024 + bn * 128) * 512;
    f32x4 acc[4][4] = {};
    gemm_nt_core(A, B, 512, 512, 512, lA, lB, acc);

    const int lane = threadIdx.x & 63;
    const int wave = threadIdx.x >> 6;
    const int wm = (wave >> 1) * 64;
    const int wn = (wave & 1) * 64;
    const int fr = lane & 15;
    const int fk = lane >> 4;

    #pragma unroll
    for (int m = 0; m < 4; ++m) {
        int m0 = bm * 128 + wm + m * 16 + fk * 4;
        #pragma unroll
        for (int n = 0; n < 4; ++n) {
            int ncol = bn * 128 + wn + n * 16 + fr;
            f32x4 a = acc[m][n];
            short4 sv;
            sv.x = f2bf(a[0]); sv.y = f2bf(a[1]); sv.z = f2bf(a[2]); sv.w = f2bf(a[3]);
            *(short4*)&S[((size_t)(b * 1024 + ncol)) * 1024 + m0] = sv;
        }
    }
}

// ---------------- K5: row softmax in place on S (bf16) ----------------
__global__ __launch_bounds__(256) void softmax_rows(short* __restrict__ S)
{
    const int wave = threadIdx.x >> 6;
    const int lane = threadIdx.x & 63;
    size_t row = (size_t)blockIdx.x * 4 + wave;  // 16384 rows
    short* p = S + row * 1024;
    short4 raw[4];
    float v[16];
    #pragma unroll
    for (int i = 0; i < 4; ++i) raw[i] = ((short4*)p)[lane + 64 * i];
    #pragma unroll
    for (int i = 0; i < 4; ++i) {
        v[i * 4 + 0] = bf2f(raw[i].x);
        v[i * 4 + 1] = bf2f(raw[i].y);
        v[i * 4 + 2] = bf2f(raw[i].z);
        v[i * 4 + 3] = bf2f(raw[i].w);
    }
    float mx = v[0];
    #pragma unroll
    for (int i = 1; i < 16; ++i) mx = fmaxf(mx, v[i]);
    #pragma unroll
    for (int o = 1; o < 64; o <<= 1) mx = fmaxf(mx, __shfl_xor(mx, o));
    float sum = 0.f;
    #pragma unroll
    for (int i = 0; i < 16; ++i) { v[i] = __expf(v[i] - mx); sum += v[i]; }
    #pragma unroll
    for (int o = 1; o < 64; o <<= 1) sum += __shfl_xor(sum, o);
    float inv = 1.f / sum;
    #pragma unroll
    for (int i = 0; i < 4; ++i) {
        short4 sv;
        sv.x = f2bf(v[i * 4 + 0] * inv);
        sv.y = f2bf(v[i * 4 + 1] * inv);
        sv.z = f2bf(v[i * 4 + 2] * inv);
        sv.w = f2bf(v[i * 4 + 3] * inv);
        ((short4*)p)[lane + 64 * i] = sv;
    }
}

// ---------------- K6: h = P.v  (A=v rows c, B=P rows n) -> h[b,n,c] bf16 ----------------
__global__ __launch_bounds__(256) void pv_gemm(
    const short* __restrict__ vv, const short* __restrict__ P, short* __restrict__ h)
{
    __shared__ short lA[128 * 32], lB[128 * 32];
    const int b  = blockIdx.z;
    const int bm = blockIdx.y;   // 0..3 over c=512
    const int bn = blockIdx.x;   // 0..7 over n=1024
    const short* A = vv + ((size_t)b * 512 + bm * 128) * 1024;
    const short* B = P + ((size_t)b * 1024 + bn * 128) * 1024;
    f32x4 acc[4][4] = {};
    gemm_nt_core(A, B, 1024, 1024, 1024, lA, lB, acc);

    const int lane = threadIdx.x & 63;
    const int wave = threadIdx.x >> 6;
    const int wm = (wave >> 1) * 64;
    const int wn = (wave & 1) * 64;
    const int fr = lane & 15;
    const int fk = lane >> 4;

    #pragma unroll
    for (int m = 0; m < 4; ++m) {
        int c0 = bm * 128 + wm + m * 16 + fk * 4;
        #pragma unroll
        for (int n = 0; n < 4; ++n) {
            int ncol = bn * 128 + wn + n * 16 + fr;
            f32x4 a = acc[m][n];
            short4 sv;
            sv.x = f2bf(a[0]); sv.y = f2bf(a[1]); sv.z = f2bf(a[2]); sv.w = f2bf(a[3]);
            *(short4*)&h[((size_t)(b * 1024 + ncol)) * 512 + c0] = sv;
        }
    }
}

// ---------------- K7: out = proj_w.h + proj_b + x ----------------
__global__ __launch_bounds__(256) void proj_gemm(
    const short* __restrict__ wp, const float* __restrict__ proj_b,
    const short* __restrict__ h, const float* __restrict__ x, float* __restrict__ out)
{
    __shared__ short lA[128 * 32], lB[128 * 32];
    const int b  = blockIdx.z;
    const int bm = blockIdx.y;   // 0..3 over o=512
    const int bn = blockIdx.x;   // 0..7 over n=1024
    const short* A = wp + (size_t)bm * 128 * 512;
    const short* B = h + ((size_t)b * 1024 + bn * 128) * 512;
    f32x4 acc[4][4] = {};
    gemm_nt_core(A, B, 512, 512, 512, lA, lB, acc);

    const int lane = threadIdx.x & 63;
    const int wave = threadIdx.x >> 6;
    const int wm = (wave >> 1) * 64;
    const int wn = (wave & 1) * 64;
    const int fr = lane & 15;
    const int fk = lane >> 4;

    #pragma unroll
    for (int m = 0; m < 4; ++m) {
        int o0 = bm * 128 + wm + m * 16 + fk * 4;
        float4 pb = *(const float4*)&proj_b[o0];
        float pb4[4] = {pb.x, pb.y, pb.z, pb.w};
        #pragma unroll
        for (int n = 0; n < 4; ++n) {
            int col = bn * 128 + wn + n * 16 + fr;
            f32x4 a = acc[m][n];
            #pragma unroll
            for (int r = 0; r < 4; ++r) {
                size_t idx = ((size_t)(b * 512 + o0 + r)) * 1024 + col;
                out[idx] = a[r] + pb4[r] + x[idx];
            }
        }
    }
}

extern "C" void kernel_launch(void* const* d_in, const int* in_sizes, int n_in,
                              void* d_out, int out_size, void* d_ws, size_t ws_size,
                              hipStream_t stream) {
    const float* x      = (const float*)d_in[0];
    const float* norm_w = (const float*)d_in[1];
    const float* norm_b = (const float*)d_in[2];
    const float* qkv_w  = (const float*)d_in[3];
    const float* qkv_b  = (const float*)d_in[4];
    const float* proj_w = (const float*)d_in[5];
    const float* proj_b = (const float*)d_in[6];
    float* out = (float*)d_out;

    char* ws = (char*)d_ws;
    size_t off = 0;
    auto alloc = [&](size_t bytes) {
        void* p = ws + off;
        off = (off + bytes + 255) & ~(size_t)255;
        return p;
    };
    float* mean = (float*)alloc(512 * 4);
    float* rstd = (float*)alloc(512 * 4);
    short* wq   = (short*)alloc((size_t)1536 * 512 * 2);
    short* wp   = (short*)alloc((size_t)512 * 512 * 2);
    short* xnT  = (short*)alloc((size_t)16 * 1024 * 512 * 2);
    short* qT   = (short*)alloc((size_t)16 * 1024 * 512 * 2);
    short* kT   = (short*)alloc((size_t)16 * 1024 * 512 * 2);
    short* vv   = (short*)alloc((size_t)16 * 512 * 1024 * 2);
    short* S    = (short*)alloc((size_t)16 * 1024 * 1024 * 2);
    short* h    = xnT;  // alias: xnT dead after qkv_gemm

    cvt_weights<<<1024, 256, 0, stream>>>(qkv_w, proj_w, wq, wp);
    gn_stats<<<512, 256, 0, stream>>>(x, mean, rstd);
    gn_apply_t<<<dim3(16, 8, 16), 256, 0, stream>>>(x, norm_w, norm_b, mean, rstd, xnT);
    qkv_gemm<<<dim3(8, 12, 16), 256, 0, stream>>>(wq, qkv_b, xnT, qT, kT, vv);
    s_gemm<<<dim3(8, 8, 16), 256, 0, stream>>>(kT, qT, S);
    softmax_rows<<<4096, 256, 0, stream>>>(S);
    pv_gemm<<<dim3(8, 4, 16), 256, 0, stream>>>(vv, S, h);
    proj_gemm<<<dim3(8, 4, 16), 256, 0, stream>>>(wp, proj_b, h, x, out);
}

// Round 3
// 247.305 us; speedup vs baseline: 1.0302x; 1.0302x over previous
//
#include <hip/hip_runtime.h>

#define GLD16(gp, lp) __builtin_amdgcn_global_load_lds( \
    (const __attribute__((address_space(1))) void*)(gp), \
    (__attribute__((address_space(3))) void*)(lp), 16, 0, 0)

typedef __attribute__((ext_vector_type(8))) short bf16x8;
typedef __attribute__((ext_vector_type(4))) float f32x4;

__device__ __forceinline__ short f2bf(float f) {
    union { float f; unsigned u; } x; x.f = f;
    unsigned r = x.u + 0x7fffu + ((x.u >> 16) & 1u);
    return (short)(r >> 16);
}
__device__ __forceinline__ float bf2f(short s) {
    union { unsigned u; float f; } x;
    x.u = ((unsigned)(unsigned short)s) << 16;
    return x.f;
}

// ---------------- K0: weights fp32 -> bf16 ----------------
__global__ __launch_bounds__(256) void cvt_weights(
    const float* __restrict__ qkv_w, const float* __restrict__ proj_w,
    short* __restrict__ wq, short* __restrict__ wp)
{
    int idx = blockIdx.x * 256 + threadIdx.x;   // 262144 float4s total
    const int NQ4 = (1536 * 512) / 4;           // 196608
    float4 f; short4 s;
    if (idx < NQ4) {
        f = ((const float4*)qkv_w)[idx];
        s.x = f2bf(f.x); s.y = f2bf(f.y); s.z = f2bf(f.z); s.w = f2bf(f.w);
        ((short4*)wq)[idx] = s;
    } else {
        int j = idx - NQ4;                      // 65536 for proj
        f = ((const float4*)proj_w)[j];
        s.x = f2bf(f.x); s.y = f2bf(f.y); s.z = f2bf(f.z); s.w = f2bf(f.w);
        ((short4*)wp)[j] = s;
    }
}

// ---------------- K1: groupnorm stats ----------------
__global__ __launch_bounds__(256) void gn_stats(
    const float* __restrict__ x, float* __restrict__ mean, float* __restrict__ rstd)
{
    int bg = blockIdx.x;  // 0..511
    const float4* p = (const float4*)(x + (size_t)bg * 16384);
    float s = 0.f, ss = 0.f;
    for (int i = threadIdx.x; i < 4096; i += 256) {
        float4 v = p[i];
        s  += v.x + v.y + v.z + v.w;
        ss += v.x * v.x + v.y * v.y + v.z * v.z + v.w * v.w;
    }
    #pragma unroll
    for (int o = 32; o > 0; o >>= 1) {
        s  += __shfl_down(s, o);
        ss += __shfl_down(ss, o);
    }
    __shared__ float ls[4], lss[4];
    int wave = threadIdx.x >> 6;
    if ((threadIdx.x & 63) == 0) { ls[wave] = s; lss[wave] = ss; }
    __syncthreads();
    if (threadIdx.x == 0) {
        s  = ls[0] + ls[1] + ls[2] + ls[3];
        ss = lss[0] + lss[1] + lss[2] + lss[3];
        float m = s * (1.f / 16384.f);
        float var = ss * (1.f / 16384.f) - m * m;
        mean[bg] = m;
        rstd[bg] = rsqrtf(var + 1e-5f);
    }
}

// ---------------- K2: normalize + transpose -> xnT [B,HW,C] bf16 ----------------
__global__ __launch_bounds__(256) void gn_apply_t(
    const float* __restrict__ x, const float* __restrict__ w, const float* __restrict__ bb,
    const float* __restrict__ mean, const float* __restrict__ rstd,
    short* __restrict__ xnT)
{
    __shared__ short tile[64][65];
    int b = blockIdx.z, cblk = blockIdx.y, nblk = blockIdx.x;
    int t = threadIdx.x;
    int nl = t & 63;
    int cb = t >> 6;  // 0..3
    #pragma unroll
    for (int i = 0; i < 16; ++i) {
        int cl = cb * 16 + i;
        int cg = cblk * 64 + cl;
        int bgid = b * 32 + (cg >> 4);
        float sc = rstd[bgid] * w[cg];
        float sh = bb[cg] - mean[bgid] * sc;
        float xv = x[((size_t)(b * 512 + cg)) * 1024 + nblk * 64 + nl];
        tile[cl][nl] = f2bf(xv * sc + sh);
    }
    __syncthreads();
    int ng = t >> 4;            // 0..15
    int c4 = (t & 15) * 4;
    #pragma unroll
    for (int p = 0; p < 4; ++p) {
        int nl2 = p * 16 + ng;
        short4 sv;
        sv.x = tile[c4 + 0][nl2];
        sv.y = tile[c4 + 1][nl2];
        sv.z = tile[c4 + 2][nl2];
        sv.w = tile[c4 + 3][nl2];
        *(short4*)&xnT[((size_t)(b * 1024 + nblk * 64 + nl2)) * 512 + cblk * 64 + c4] = sv;
    }
}

// ======== 256x256 pipelined NT-GEMM core: BK=64, 8 waves (2Mx4N) ========
// A: [M][K] row-major bf16 (256 rows at A), B: [N][K] row-major bf16 (256 rows).
// LDS: 2 buffers x (A 256x64 + B 256x64) = 128 KiB. XOR-swizzled 16B slots
// (slot ^= row&7) on BOTH the pre-swizzled global source (linear gload_lds
// dest) and the ds_read addresses. Counted vmcnt(4) at tile boundary.
// acc[8][4]: per-wave 128(M) x 64(N) output.
__device__ __forceinline__ void gemm256(
    const short* __restrict__ A, const short* __restrict__ B,
    const int lda, const int ldb, const int NT,
    short* lds, f32x4 acc[8][4])
{
    const int tid  = threadIdx.x;
    const int lane = tid & 63;
    const int wave = tid >> 6;
    const int wm = wave >> 2;        // 0..1
    const int wn = wave & 3;         // 0..3
    const int fr = lane & 15;
    const int fk = lane >> 4;        // 0..3
    const int frx = fr & 7;

    // staging: 4 A-chunks + 4 B-chunks of 16B per thread per K-tile
    const short* pa[4]; const short* pb[4];
    int la[4], lb[4];
    #pragma unroll
    for (int i = 0; i < 4; ++i) {
        int cid = i * 512 + tid;       // 0..2047
        int row = cid >> 3;            // 0..255
        int sl  = cid & 7;             // 16B slot in row
        int csw = sl ^ (row & 7);      // pre-swizzled global chunk
        pa[i] = A + (size_t)row * lda + csw * 8;
        pb[i] = B + (size_t)row * ldb + csw * 8;
        la[i] = cid * 8;               // linear LDS dest (shorts), A region
        lb[i] = 16384 + cid * 8;       // B region
    }

    // prologue: stage tile 0 into buf0
    #pragma unroll
    for (int i = 0; i < 4; ++i) GLD16(pa[i], lds + la[i]);
    #pragma unroll
    for (int i = 0; i < 4; ++i) GLD16(pb[i], lds + lb[i]);
    #pragma unroll
    for (int i = 0; i < 4; ++i) { pa[i] += 64; pb[i] += 64; }

    const int arow0 = wm * 128 + fr;
    const int brow0 = wn * 64 + fr;
    const int slot0 = (fk ^ frx) << 3;        // ks=0 swizzled slot (shorts)
    const int slot1 = ((4 + fk) ^ frx) << 3;  // ks=1

    for (int t = 0; t < NT; ++t) {
        const int cur = (t & 1) << 15;    // 0 / 32768 shorts
        const int nxt = 32768 - cur;
        const bool pre = (t + 1 < NT);

        if (pre) {  // phase-A staging: next tile's A half
            #pragma unroll
            for (int i = 0; i < 4; ++i) GLD16(pa[i], lds + nxt + la[i]);
        }
        if (pre) asm volatile("s_waitcnt vmcnt(4)" ::: "memory");
        else     asm volatile("s_waitcnt vmcnt(0)" ::: "memory");
        asm volatile("s_barrier" ::: "memory");
        __builtin_amdgcn_sched_barrier(0);

        bf16x8 af[8], bfr[4];
        // ---- k-sub 0 ----
        #pragma unroll
        for (int m = 0; m < 8; ++m)
            af[m] = *(const bf16x8*)&lds[cur + ((arow0 + m * 16) << 6) + slot0];
        #pragma unroll
        for (int n = 0; n < 4; ++n)
            bfr[n] = *(const bf16x8*)&lds[cur + 16384 + ((brow0 + n * 16) << 6) + slot0];
        if (pre) {  // phase-B staging: next tile's B half
            #pragma unroll
            for (int i = 0; i < 4; ++i) GLD16(pb[i], lds + nxt + lb[i]);
        }
        __builtin_amdgcn_s_setprio(1);
        #pragma unroll
        for (int m = 0; m < 8; ++m)
            #pragma unroll
            for (int n = 0; n < 4; ++n)
                acc[m][n] = __builtin_amdgcn_mfma_f32_16x16x32_bf16(af[m], bfr[n], acc[m][n], 0, 0, 0);
        __builtin_amdgcn_s_setprio(0);

        // ---- k-sub 1 ----
        #pragma unroll
        for (int m = 0; m < 8; ++m)
            af[m] = *(const bf16x8*)&lds[cur + ((arow0 + m * 16) << 6) + slot1];
        #pragma unroll
        for (int n = 0; n < 4; ++n)
            bfr[n] = *(const bf16x8*)&lds[cur + 16384 + ((brow0 + n * 16) << 6) + slot1];
        __builtin_amdgcn_s_setprio(1);
        #pragma unroll
        for (int m = 0; m < 8; ++m)
            #pragma unroll
            for (int n = 0; n < 4; ++n)
                acc[m][n] = __builtin_amdgcn_mfma_f32_16x16x32_bf16(af[m], bfr[n], acc[m][n], 0, 0, 0);
        __builtin_amdgcn_s_setprio(0);

        if (pre) {
            #pragma unroll
            for (int i = 0; i < 4; ++i) { pa[i] += 64; pb[i] += 64; }
        }
        asm volatile("s_barrier" ::: "memory");  // buf[cur] reads done -> re-stageable
        __builtin_amdgcn_sched_barrier(0);
    }
}

#define GEMM_EPI_IDX() \
    const int lane = threadIdx.x & 63; \
    const int wave = threadIdx.x >> 6; \
    const int wm = wave >> 2; \
    const int wn = wave & 3; \
    const int fq = lane >> 4; \
    const int fcol = lane & 15;

// ---------------- K3: QKV GEMM (M=1536 over wq rows, N=1024 spatial) ----------------
__global__ __launch_bounds__(512, 2) void qkv_gemm(
    const short* __restrict__ wq, const float* __restrict__ qkv_b,
    const short* __restrict__ xnT,
    short* __restrict__ qT, short* __restrict__ kT, short* __restrict__ vv)
{
    __shared__ short lds[65536];
    const int b = blockIdx.z, bm = blockIdx.y, bn = blockIdx.x;
    const short* A  = wq + (size_t)bm * 256 * 512;
    const short* Bb = xnT + ((size_t)b * 1024 + bn * 256) * 512;
    f32x4 acc[8][4];
    #pragma unroll
    for (int m = 0; m < 8; ++m)
        #pragma unroll
        for (int n = 0; n < 4; ++n) acc[m][n] = (f32x4){0.f, 0.f, 0.f, 0.f};
    gemm256(A, Bb, 512, 512, 8, lds, acc);

    GEMM_EPI_IDX();
    const int region = bm >> 1;  // 0=q 1=k 2=v
    const float qscale = 0.04419417382415922f;  // 1/sqrt(512)

    #pragma unroll
    for (int m = 0; m < 8; ++m) {
        int o0 = bm * 256 + wm * 128 + m * 16 + fq * 4;
        float4 bias = *(const float4*)&qkv_b[o0];
        float bb4[4] = {bias.x, bias.y, bias.z, bias.w};
        #pragma unroll
        for (int n = 0; n < 4; ++n) {
            int col = bn * 256 + wn * 64 + n * 16 + fcol;
            f32x4 a = acc[m][n];
            if (region == 0) {
                short4 sv;
                sv.x = f2bf((a[0] + bb4[0]) * qscale);
                sv.y = f2bf((a[1] + bb4[1]) * qscale);
                sv.z = f2bf((a[2] + bb4[2]) * qscale);
                sv.w = f2bf((a[3] + bb4[3]) * qscale);
                *(short4*)&qT[((size_t)(b * 1024 + col)) * 512 + o0] = sv;
            } else if (region == 1) {
                short4 sv;
                sv.x = f2bf(a[0] + bb4[0]);
                sv.y = f2bf(a[1] + bb4[1]);
                sv.z = f2bf(a[2] + bb4[2]);
                sv.w = f2bf(a[3] + bb4[3]);
                *(short4*)&kT[((size_t)(b * 1024 + col)) * 512 + (o0 - 512)] = sv;
            } else {
                #pragma unroll
                for (int r = 0; r < 4; ++r)
                    vv[((size_t)(b * 512 + (o0 - 1024 + r))) * 1024 + col] = f2bf(a[r] + bb4[r]);
            }
        }
    }
}

// ---------------- K4: S = q.kT -> S[b,n,m] bf16 ----------------
__global__ __launch_bounds__(512, 2) void s_gemm(
    const short* __restrict__ kT, const short* __restrict__ qT, short* __restrict__ S)
{
    __shared__ short lds[65536];
    const int b = blockIdx.z, bm = blockIdx.y, bn = blockIdx.x;
    const short* A  = kT + ((size_t)b * 1024 + bm * 256) * 512;
    const short* Bb = qT + ((size_t)b * 1024 + bn * 256) * 512;
    f32x4 acc[8][4];
    #pragma unroll
    for (int m = 0; m < 8; ++m)
        #pragma unroll
        for (int n = 0; n < 4; ++n) acc[m][n] = (f32x4){0.f, 0.f, 0.f, 0.f};
    gemm256(A, Bb, 512, 512, 8, lds, acc);

    GEMM_EPI_IDX();
    #pragma unroll
    for (int m = 0; m < 8; ++m) {
        int m0 = bm * 256 + wm * 128 + m * 16 + fq * 4;
        #pragma unroll
        for (int n = 0; n < 4; ++n) {
            int ncol = bn * 256 + wn * 64 + n * 16 + fcol;
            f32x4 a = acc[m][n];
            short4 sv;
            sv.x = f2bf(a[0]); sv.y = f2bf(a[1]); sv.z = f2bf(a[2]); sv.w = f2bf(a[3]);
            *(short4*)&S[((size_t)(b * 1024 + ncol)) * 1024 + m0] = sv;
        }
    }
}

// ---------------- K5: row softmax in place on S (bf16) ----------------
__global__ __launch_bounds__(256) void softmax_rows(short* __restrict__ S)
{
    const int wave = threadIdx.x >> 6;
    const int lane = threadIdx.x & 63;
    size_t row = (size_t)blockIdx.x * 4 + wave;  // 16384 rows
    short* p = S + row * 1024;
    short4 raw[4];
    float v[16];
    #pragma unroll
    for (int i = 0; i < 4; ++i) raw[i] = ((short4*)p)[lane + 64 * i];
    #pragma unroll
    for (int i = 0; i < 4; ++i) {
        v[i * 4 + 0] = bf2f(raw[i].x);
        v[i * 4 + 1] = bf2f(raw[i].y);
        v[i * 4 + 2] = bf2f(raw[i].z);
        v[i * 4 + 3] = bf2f(raw[i].w);
    }
    float mx = v[0];
    #pragma unroll
    for (int i = 1; i < 16; ++i) mx = fmaxf(mx, v[i]);
    #pragma unroll
    for (int o = 1; o < 64; o <<= 1) mx = fmaxf(mx, __shfl_xor(mx, o));
    float sum = 0.f;
    #pragma unroll
    for (int i = 0; i < 16; ++i) { v[i] = __expf(v[i] - mx); sum += v[i]; }
    #pragma unroll
    for (int o = 1; o < 64; o <<= 1) sum += __shfl_xor(sum, o);
    float inv = 1.f / sum;
    #pragma unroll
    for (int i = 0; i < 4; ++i) {
        short4 sv;
        sv.x = f2bf(v[i * 4 + 0] * inv);
        sv.y = f2bf(v[i * 4 + 1] * inv);
        sv.z = f2bf(v[i * 4 + 2] * inv);
        sv.w = f2bf(v[i * 4 + 3] * inv);
        ((short4*)p)[lane + 64 * i] = sv;
    }
}

// ---------------- K6: h = P.v (M=512 over v rows c, N=1024 spatial, K=1024) ----------------
__global__ __launch_bounds__(512, 2) void pv_gemm(
    const short* __restrict__ vv, const short* __restrict__ P, short* __restrict__ h)
{
    __shared__ short lds[65536];
    const int b = blockIdx.z, bm = blockIdx.y, bn = blockIdx.x;
    const short* A  = vv + ((size_t)b * 512 + bm * 256) * 1024;
    const short* Bb = P + ((size_t)b * 1024 + bn * 256) * 1024;
    f32x4 acc[8][4];
    #pragma unroll
    for (int m = 0; m < 8; ++m)
        #pragma unroll
        for (int n = 0; n < 4; ++n) acc[m][n] = (f32x4){0.f, 0.f, 0.f, 0.f};
    gemm256(A, Bb, 1024, 1024, 16, lds, acc);

    GEMM_EPI_IDX();
    #pragma unroll
    for (int m = 0; m < 8; ++m) {
        int c0 = bm * 256 + wm * 128 + m * 16 + fq * 4;
        #pragma unroll
        for (int n = 0; n < 4; ++n) {
            int ncol = bn * 256 + wn * 64 + n * 16 + fcol;
            f32x4 a = acc[m][n];
            short4 sv;
            sv.x = f2bf(a[0]); sv.y = f2bf(a[1]); sv.z = f2bf(a[2]); sv.w = f2bf(a[3]);
            *(short4*)&h[((size_t)(b * 1024 + ncol)) * 512 + c0] = sv;
        }
    }
}

// ---------------- K7: out = proj_w.h + proj_b + x ----------------
__global__ __launch_bounds__(512, 2) void proj_gemm(
    const short* __restrict__ wp, const float* __restrict__ proj_b,
    const short* __restrict__ h, const float* __restrict__ x, float* __restrict__ out)
{
    __shared__ short lds[65536];
    const int b = blockIdx.z, bm = blockIdx.y, bn = blockIdx.x;
    const short* A  = wp + (size_t)bm * 256 * 512;
    const short* Bb = h + ((size_t)b * 1024 + bn * 256) * 512;
    f32x4 acc[8][4];
    #pragma unroll
    for (int m = 0; m < 8; ++m)
        #pragma unroll
        for (int n = 0; n < 4; ++n) acc[m][n] = (f32x4){0.f, 0.f, 0.f, 0.f};
    gemm256(A, Bb, 512, 512, 8, lds, acc);

    GEMM_EPI_IDX();
    #pragma unroll
    for (int m = 0; m < 8; ++m) {
        int o0 = bm * 256 + wm * 128 + m * 16 + fq * 4;
        float4 pb = *(const float4*)&proj_b[o0];
        float pb4[4] = {pb.x, pb.y, pb.z, pb.w};
        #pragma unroll
        for (int n = 0; n < 4; ++n) {
            int col = bn * 256 + wn * 64 + n * 16 + fcol;
            f32x4 a = acc[m][n];
            #pragma unroll
            for (int r = 0; r < 4; ++r) {
                size_t idx = ((size_t)(b * 512 + o0 + r)) * 1024 + col;
                out[idx] = a[r] + pb4[r] + x[idx];
            }
        }
    }
}

extern "C" void kernel_launch(void* const* d_in, const int* in_sizes, int n_in,
                              void* d_out, int out_size, void* d_ws, size_t ws_size,
                              hipStream_t stream) {
    const float* x      = (const float*)d_in[0];
    const float* norm_w = (const float*)d_in[1];
    const float* norm_b = (const float*)d_in[2];
    const float* qkv_w  = (const float*)d_in[3];
    const float* qkv_b  = (const float*)d_in[4];
    const float* proj_w = (const float*)d_in[5];
    const float* proj_b = (const float*)d_in[6];
    float* out = (float*)d_out;

    char* ws = (char*)d_ws;
    size_t off = 0;
    auto alloc = [&](size_t bytes) {
        void* p = ws + off;
        off = (off + bytes + 255) & ~(size_t)255;
        return p;
    };
    float* mean = (float*)alloc(512 * 4);
    float* rstd = (float*)alloc(512 * 4);
    short* wq   = (short*)alloc((size_t)1536 * 512 * 2);
    short* wp   = (short*)alloc((size_t)512 * 512 * 2);
    short* xnT  = (short*)alloc((size_t)16 * 1024 * 512 * 2);
    short* qT   = (short*)alloc((size_t)16 * 1024 * 512 * 2);
    short* kT   = (short*)alloc((size_t)16 * 1024 * 512 * 2);
    short* vv   = (short*)alloc((size_t)16 * 512 * 1024 * 2);
    short* S    = (short*)alloc((size_t)16 * 1024 * 1024 * 2);
    short* h    = xnT;  // alias: xnT dead after qkv_gemm

    cvt_weights<<<1024, 256, 0, stream>>>(qkv_w, proj_w, wq, wp);
    gn_stats<<<512, 256, 0, stream>>>(x, mean, rstd);
    gn_apply_t<<<dim3(16, 8, 16), 256, 0, stream>>>(x, norm_w, norm_b, mean, rstd, xnT);
    qkv_gemm<<<dim3(4, 6, 16), 512, 0, stream>>>(wq, qkv_b, xnT, qT, kT, vv);
    s_gemm<<<dim3(4, 4, 16), 512, 0, stream>>>(kT, qT, S);
    softmax_rows<<<4096, 256, 0, stream>>>(S);
    pv_gemm<<<dim3(4, 2, 16), 512, 0, stream>>>(vv, S, h);
    proj_gemm<<<dim3(4, 2, 16), 512, 0, stream>>>(wp, proj_b, h, x, out);
}

// Round 4
// 243.083 us; speedup vs baseline: 1.0481x; 1.0174x over previous
//
#include <hip/hip_runtime.h>

#define GLD16(gp, lp) __builtin_amdgcn_global_load_lds( \
    (const __attribute__((address_space(1))) void*)(gp), \
    (__attribute__((address_space(3))) void*)(lp), 16, 0, 0)

typedef __attribute__((ext_vector_type(8))) short bf16x8;
typedef __attribute__((ext_vector_type(4))) float f32x4;

__device__ __forceinline__ short f2bf(float f) {
    union { float f; unsigned u; } x; x.f = f;
    unsigned r = x.u + 0x7fffu + ((x.u >> 16) & 1u);
    return (short)(r >> 16);
}
__device__ __forceinline__ float bf2f(short s) {
    union { unsigned u; float f; } x;
    x.u = ((unsigned)(unsigned short)s) << 16;
    return x.f;
}

// ---------------- K0: weights fp32 -> bf16 ----------------
__global__ __launch_bounds__(256) void cvt_weights(
    const float* __restrict__ qkv_w, const float* __restrict__ proj_w,
    short* __restrict__ wq, short* __restrict__ wp)
{
    int idx = blockIdx.x * 256 + threadIdx.x;   // 262144 float4s total
    const int NQ4 = (1536 * 512) / 4;           // 196608
    float4 f; short4 s;
    if (idx < NQ4) {
        f = ((const float4*)qkv_w)[idx];
        s.x = f2bf(f.x); s.y = f2bf(f.y); s.z = f2bf(f.z); s.w = f2bf(f.w);
        ((short4*)wq)[idx] = s;
    } else {
        int j = idx - NQ4;                      // 65536 for proj
        f = ((const float4*)proj_w)[j];
        s.x = f2bf(f.x); s.y = f2bf(f.y); s.z = f2bf(f.z); s.w = f2bf(f.w);
        ((short4*)wp)[j] = s;
    }
}

// ---------------- K1: groupnorm stats ----------------
__global__ __launch_bounds__(256) void gn_stats(
    const float* __restrict__ x, float* __restrict__ mean, float* __restrict__ rstd)
{
    int bg = blockIdx.x;  // 0..511
    const float4* p = (const float4*)(x + (size_t)bg * 16384);
    float s = 0.f, ss = 0.f;
    for (int i = threadIdx.x; i < 4096; i += 256) {
        float4 v = p[i];
        s  += v.x + v.y + v.z + v.w;
        ss += v.x * v.x + v.y * v.y + v.z * v.z + v.w * v.w;
    }
    #pragma unroll
    for (int o = 32; o > 0; o >>= 1) {
        s  += __shfl_down(s, o);
        ss += __shfl_down(ss, o);
    }
    __shared__ float ls[4], lss[4];
    int wave = threadIdx.x >> 6;
    if ((threadIdx.x & 63) == 0) { ls[wave] = s; lss[wave] = ss; }
    __syncthreads();
    if (threadIdx.x == 0) {
        s  = ls[0] + ls[1] + ls[2] + ls[3];
        ss = lss[0] + lss[1] + lss[2] + lss[3];
        float m = s * (1.f / 16384.f);
        float var = ss * (1.f / 16384.f) - m * m;
        mean[bg] = m;
        rstd[bg] = rsqrtf(var + 1e-5f);
    }
}

// ---------------- K2: normalize + transpose -> xnT [B,HW,C] bf16 ----------------
__global__ __launch_bounds__(256) void gn_apply_t(
    const float* __restrict__ x, const float* __restrict__ w, const float* __restrict__ bb,
    const float* __restrict__ mean, const float* __restrict__ rstd,
    short* __restrict__ xnT)
{
    __shared__ short tile[64][65];
    int b = blockIdx.z, cblk = blockIdx.y, nblk = blockIdx.x;
    int t = threadIdx.x;
    int nl = t & 63;
    int cb = t >> 6;  // 0..3
    #pragma unroll
    for (int i = 0; i < 16; ++i) {
        int cl = cb * 16 + i;
        int cg = cblk * 64 + cl;
        int bgid = b * 32 + (cg >> 4);
        float sc = rstd[bgid] * w[cg];
        float sh = bb[cg] - mean[bgid] * sc;
        float xv = x[((size_t)(b * 512 + cg)) * 1024 + nblk * 64 + nl];
        tile[cl][nl] = f2bf(xv * sc + sh);
    }
    __syncthreads();
    int ng = t >> 4;            // 0..15
    int c4 = (t & 15) * 4;
    #pragma unroll
    for (int p = 0; p < 4; ++p) {
        int nl2 = p * 16 + ng;
        short4 sv;
        sv.x = tile[c4 + 0][nl2];
        sv.y = tile[c4 + 1][nl2];
        sv.z = tile[c4 + 2][nl2];
        sv.w = tile[c4 + 3][nl2];
        *(short4*)&xnT[((size_t)(b * 1024 + nblk * 64 + nl2)) * 512 + cblk * 64 + c4] = sv;
    }
}

// ======== deep-prefetch NT-GEMM core: 256(M) x BN, BK=32, 8 waves (2Mx4N) ========
// A: [256][K] row-major bf16, B: [BN][K] row-major bf16 (NT: both K-contig).
// 4-deep LDS ring: buffer = A 256x32 + B BNx32 shorts. Tiles t+1..t+3 in
// flight -> vmcnt wait for t+1 sits ~3 tiles behind issue (covers L3 latency).
// One barrier per K-tile; counted vmcnt (never 0 in steady state).
// Swizzle: 16B slot ^= (row>>1)&3 on BOTH pre-swizzled global source (linear
// gload_lds dest) and ds_read addresses -> max 2-way bank alias (free).
// NFR = BN/64 = B fragments per wave (per-wave output 128 x BN/4).
template<int NFR, int NT>
__device__ __forceinline__ void gemm_core(
    const short* __restrict__ A, const short* __restrict__ B,
    const int lda, const int ldb, short* lds, f32x4 acc[8][NFR])
{
    constexpr int BCH = NFR / 2;              // B staging chunks/thread (2 or 1)
    constexpr int BUF = 8192 + NFR * 2048;    // shorts per ring buffer
    constexpr int LPS = 2 + BCH;              // GLD16 per thread per stage
    const int tid  = threadIdx.x;
    const int lane = tid & 63;
    const int wave = tid >> 6;
    const int wm = wave >> 2;        // 0..1
    const int wn = wave & 3;         // 0..3
    const int fr = lane & 15;
    const int fk = lane >> 4;        // 0..3

    const short* pa[2]; int la[2];
    const short* pb[BCH]; int lb[BCH];
    #pragma unroll
    for (int i = 0; i < 2; ++i) {
        int cid = i * 512 + tid;               // 0..1023 -> A rows 0..255
        int row = cid >> 2, sl = cid & 3;
        int csw = sl ^ ((row >> 1) & 3);       // pre-swizzled 16B slot
        pa[i] = A + (size_t)row * lda + csw * 8;
        la[i] = cid * 8;                       // linear LDS dest (shorts)
    }
    #pragma unroll
    for (int i = 0; i < BCH; ++i) {
        int cid = i * 512 + tid;
        int row = cid >> 2, sl = cid & 3;
        int csw = sl ^ ((row >> 1) & 3);
        pb[i] = B + (size_t)row * ldb + csw * 8;
        lb[i] = 8192 + cid * 8;
    }

    auto stage = [&](int t) {
        const int base = (t & 3) * BUF;
        const int koff = t * 32;
        #pragma unroll
        for (int i = 0; i < 2; ++i) GLD16(pa[i] + koff, lds + base + la[i]);
        #pragma unroll
        for (int i = 0; i < BCH; ++i) GLD16(pb[i] + koff, lds + base + lb[i]);
    };

    stage(0); stage(1); stage(2);
    asm volatile("s_waitcnt vmcnt(%0)" :: "n"(2 * LPS) : "memory");  // tile 0 landed
    asm volatile("s_barrier" ::: "memory");

    const int arow0 = wm * 128 + fr;
    const int brow0 = wn * (NFR * 16) + fr;

    for (int t = 0; t < NT; ++t) {
        const int base = (t & 3) * BUF;
        bf16x8 af[8], bfr[NFR];
        #pragma unroll
        for (int m = 0; m < 8; ++m) {
            int R = arow0 + m * 16;
            af[m] = *(const bf16x8*)&lds[base + R * 32 + ((fk ^ ((R >> 1) & 3)) << 3)];
        }
        #pragma unroll
        for (int n = 0; n < NFR; ++n) {
            int R = brow0 + n * 16;
            bfr[n] = *(const bf16x8*)&lds[base + 8192 + R * 32 + ((fk ^ ((R >> 1) & 3)) << 3)];
        }
        __builtin_amdgcn_s_setprio(1);
        #pragma unroll
        for (int m = 0; m < 8; ++m)
            #pragma unroll
            for (int n = 0; n < NFR; ++n)
                acc[m][n] = __builtin_amdgcn_mfma_f32_16x16x32_bf16(af[m], bfr[n], acc[m][n], 0, 0, 0);
        __builtin_amdgcn_s_setprio(0);

        if (t + 3 < NT) stage(t + 3);          // keep ring 3 ahead
        if (t + 1 < NT) {
            // wait tile t+1 complete; allow newer stages to stay in flight
            if (t + 3 < NT)
                asm volatile("s_waitcnt vmcnt(%0)" :: "n"(2 * LPS) : "memory");
            else if (t + 2 < NT)
                asm volatile("s_waitcnt vmcnt(%0)" :: "n"(LPS) : "memory");
            else
                asm volatile("s_waitcnt vmcnt(0)" ::: "memory");
            asm volatile("s_barrier" ::: "memory");
        }
    }
}

// ---------------- K3: QKV GEMM (M=1536 over wq rows, N=1024 spatial) ----------------
__global__ __launch_bounds__(512, 2) void qkv_gemm(
    const short* __restrict__ wq, const float* __restrict__ qkv_b,
    const short* __restrict__ xnT,
    short* __restrict__ qT, short* __restrict__ kT, short* __restrict__ vv)
{
    __shared__ short lds[4 * (8192 + 4 * 2048)];
    const int b = blockIdx.z, bm = blockIdx.y, bn = blockIdx.x;
    const short* A  = wq + (size_t)bm * 256 * 512;
    const short* Bb = xnT + ((size_t)b * 1024 + bn * 256) * 512;
    f32x4 acc[8][4];
    #pragma unroll
    for (int m = 0; m < 8; ++m)
        #pragma unroll
        for (int n = 0; n < 4; ++n) acc[m][n] = (f32x4){0.f, 0.f, 0.f, 0.f};
    gemm_core<4, 16>(A, Bb, 512, 512, lds, acc);

    const int lane = threadIdx.x & 63;
    const int wave = threadIdx.x >> 6;
    const int wm = wave >> 2, wn = wave & 3;
    const int fq = lane >> 4, fcol = lane & 15;
    const int region = bm >> 1;  // 0=q 1=k 2=v
    const float qscale = 0.04419417382415922f;  // 1/sqrt(512)

    #pragma unroll
    for (int m = 0; m < 8; ++m) {
        int o0 = bm * 256 + wm * 128 + m * 16 + fq * 4;
        float4 bias = *(const float4*)&qkv_b[o0];
        float bb4[4] = {bias.x, bias.y, bias.z, bias.w};
        #pragma unroll
        for (int n = 0; n < 4; ++n) {
            int col = bn * 256 + wn * 64 + n * 16 + fcol;
            f32x4 a = acc[m][n];
            if (region == 0) {
                short4 sv;
                sv.x = f2bf((a[0] + bb4[0]) * qscale);
                sv.y = f2bf((a[1] + bb4[1]) * qscale);
                sv.z = f2bf((a[2] + bb4[2]) * qscale);
                sv.w = f2bf((a[3] + bb4[3]) * qscale);
                *(short4*)&qT[((size_t)(b * 1024 + col)) * 512 + o0] = sv;
            } else if (region == 1) {
                short4 sv;
                sv.x = f2bf(a[0] + bb4[0]);
                sv.y = f2bf(a[1] + bb4[1]);
                sv.z = f2bf(a[2] + bb4[2]);
                sv.w = f2bf(a[3] + bb4[3]);
                *(short4*)&kT[((size_t)(b * 1024 + col)) * 512 + (o0 - 512)] = sv;
            } else {
                #pragma unroll
                for (int r = 0; r < 4; ++r)
                    vv[((size_t)(b * 512 + (o0 - 1024 + r))) * 1024 + col] = f2bf(a[r] + bb4[r]);
            }
        }
    }
}

// ---------------- K4: S = q.kT -> S[b,n,m] bf16 ----------------
__global__ __launch_bounds__(512, 2) void s_gemm(
    const short* __restrict__ kT, const short* __restrict__ qT, short* __restrict__ S)
{
    __shared__ short lds[4 * (8192 + 4 * 2048)];
    const int b = blockIdx.z, bm = blockIdx.y, bn = blockIdx.x;
    const short* A  = kT + ((size_t)b * 1024 + bm * 256) * 512;
    const short* Bb = qT + ((size_t)b * 1024 + bn * 256) * 512;
    f32x4 acc[8][4];
    #pragma unroll
    for (int m = 0; m < 8; ++m)
        #pragma unroll
        for (int n = 0; n < 4; ++n) acc[m][n] = (f32x4){0.f, 0.f, 0.f, 0.f};
    gemm_core<4, 16>(A, Bb, 512, 512, lds, acc);

    const int lane = threadIdx.x & 63;
    const int wave = threadIdx.x >> 6;
    const int wm = wave >> 2, wn = wave & 3;
    const int fq = lane >> 4, fcol = lane & 15;
    #pragma unroll
    for (int m = 0; m < 8; ++m) {
        int m0 = bm * 256 + wm * 128 + m * 16 + fq * 4;
        #pragma unroll
        for (int n = 0; n < 4; ++n) {
            int ncol = bn * 256 + wn * 64 + n * 16 + fcol;
            f32x4 a = acc[m][n];
            short4 sv;
            sv.x = f2bf(a[0]); sv.y = f2bf(a[1]); sv.z = f2bf(a[2]); sv.w = f2bf(a[3]);
            *(short4*)&S[((size_t)(b * 1024 + ncol)) * 1024 + m0] = sv;
        }
    }
}

// ---------------- K5: row softmax in place on S (bf16) ----------------
__global__ __launch_bounds__(256) void softmax_rows(short* __restrict__ S)
{
    const int wave = threadIdx.x >> 6;
    const int lane = threadIdx.x & 63;
    size_t row = (size_t)blockIdx.x * 4 + wave;  // 16384 rows
    short* p = S + row * 1024;
    short4 raw[4];
    float v[16];
    #pragma unroll
    for (int i = 0; i < 4; ++i) raw[i] = ((short4*)p)[lane + 64 * i];
    #pragma unroll
    for (int i = 0; i < 4; ++i) {
        v[i * 4 + 0] = bf2f(raw[i].x);
        v[i * 4 + 1] = bf2f(raw[i].y);
        v[i * 4 + 2] = bf2f(raw[i].z);
        v[i * 4 + 3] = bf2f(raw[i].w);
    }
    float mx = v[0];
    #pragma unroll
    for (int i = 1; i < 16; ++i) mx = fmaxf(mx, v[i]);
    #pragma unroll
    for (int o = 1; o < 64; o <<= 1) mx = fmaxf(mx, __shfl_xor(mx, o));
    float sum = 0.f;
    #pragma unroll
    for (int i = 0; i < 16; ++i) { v[i] = __expf(v[i] - mx); sum += v[i]; }
    #pragma unroll
    for (int o = 1; o < 64; o <<= 1) sum += __shfl_xor(sum, o);
    float inv = 1.f / sum;
    #pragma unroll
    for (int i = 0; i < 4; ++i) {
        short4 sv;
        sv.x = f2bf(v[i * 4 + 0] * inv);
        sv.y = f2bf(v[i * 4 + 1] * inv);
        sv.z = f2bf(v[i * 4 + 2] * inv);
        sv.w = f2bf(v[i * 4 + 3] * inv);
        ((short4*)p)[lane + 64 * i] = sv;
    }
}

// ---------------- K6: h = P.v (256(M=c) x 128(N=n) tiles, K=1024) ----------------
__global__ __launch_bounds__(512, 2) void pv_gemm(
    const short* __restrict__ vv, const short* __restrict__ P, short* __restrict__ h)
{
    __shared__ short lds[4 * (8192 + 2 * 2048)];
    const int b = blockIdx.z, bm = blockIdx.y, bn = blockIdx.x;  // bn over 8
    const short* A  = vv + ((size_t)b * 512 + bm * 256) * 1024;
    const short* Bb = P + ((size_t)b * 1024 + bn * 128) * 1024;
    f32x4 acc[8][2];
    #pragma unroll
    for (int m = 0; m < 8; ++m)
        #pragma unroll
        for (int n = 0; n < 2; ++n) acc[m][n] = (f32x4){0.f, 0.f, 0.f, 0.f};
    gemm_core<2, 32>(A, Bb, 1024, 1024, lds, acc);

    const int lane = threadIdx.x & 63;
    const int wave = threadIdx.x >> 6;
    const int wm = wave >> 2, wn = wave & 3;
    const int fq = lane >> 4, fcol = lane & 15;
    #pragma unroll
    for (int m = 0; m < 8; ++m) {
        int c0 = bm * 256 + wm * 128 + m * 16 + fq * 4;
        #pragma unroll
        for (int n = 0; n < 2; ++n) {
            int ncol = bn * 128 + wn * 32 + n * 16 + fcol;
            f32x4 a = acc[m][n];
            short4 sv;
            sv.x = f2bf(a[0]); sv.y = f2bf(a[1]); sv.z = f2bf(a[2]); sv.w = f2bf(a[3]);
            *(short4*)&h[((size_t)(b * 1024 + ncol)) * 512 + c0] = sv;
        }
    }
}

// ---------------- K7: out = proj_w.h + proj_b + x (256 x 128 tiles) ----------------
__global__ __launch_bounds__(512, 2) void proj_gemm(
    const short* __restrict__ wp, const float* __restrict__ proj_b,
    const short* __restrict__ h, const float* __restrict__ x, float* __restrict__ out)
{
    __shared__ short lds[4 * (8192 + 2 * 2048)];
    const int b = blockIdx.z, bm = blockIdx.y, bn = blockIdx.x;  // bn over 8
    const short* A  = wp + (size_t)bm * 256 * 512;
    const short* Bb = h + ((size_t)b * 1024 + bn * 128) * 512;
    f32x4 acc[8][2];
    #pragma unroll
    for (int m = 0; m < 8; ++m)
        #pragma unroll
        for (int n = 0; n < 2; ++n) acc[m][n] = (f32x4){0.f, 0.f, 0.f, 0.f};
    gemm_core<2, 16>(A, Bb, 512, 512, lds, acc);

    const int lane = threadIdx.x & 63;
    const int wave = threadIdx.x >> 6;
    const int wm = wave >> 2, wn = wave & 3;
    const int fq = lane >> 4, fcol = lane & 15;
    #pragma unroll
    for (int m = 0; m < 8; ++m) {
        int o0 = bm * 256 + wm * 128 + m * 16 + fq * 4;
        float4 pb = *(const float4*)&proj_b[o0];
        float pb4[4] = {pb.x, pb.y, pb.z, pb.w};
        #pragma unroll
        for (int n = 0; n < 2; ++n) {
            int col = bn * 128 + wn * 32 + n * 16 + fcol;
            f32x4 a = acc[m][n];
            #pragma unroll
            for (int r = 0; r < 4; ++r) {
                size_t idx = ((size_t)(b * 512 + o0 + r)) * 1024 + col;
                out[idx] = a[r] + pb4[r] + x[idx];
            }
        }
    }
}

extern "C" void kernel_launch(void* const* d_in, const int* in_sizes, int n_in,
                              void* d_out, int out_size, void* d_ws, size_t ws_size,
                              hipStream_t stream) {
    const float* x      = (const float*)d_in[0];
    const float* norm_w = (const float*)d_in[1];
    const float* norm_b = (const float*)d_in[2];
    const float* qkv_w  = (const float*)d_in[3];
    const float* qkv_b  = (const float*)d_in[4];
    const float* proj_w = (const float*)d_in[5];
    const float* proj_b = (const float*)d_in[6];
    float* out = (float*)d_out;

    char* ws = (char*)d_ws;
    size_t off = 0;
    auto alloc = [&](size_t bytes) {
        void* p = ws + off;
        off = (off + bytes + 255) & ~(size_t)255;
        return p;
    };
    float* mean = (float*)alloc(512 * 4);
    float* rstd = (float*)alloc(512 * 4);
    short* wq   = (short*)alloc((size_t)1536 * 512 * 2);
    short* wp   = (short*)alloc((size_t)512 * 512 * 2);
    short* xnT  = (short*)alloc((size_t)16 * 1024 * 512 * 2);
    short* qT   = (short*)alloc((size_t)16 * 1024 * 512 * 2);
    short* kT   = (short*)alloc((size_t)16 * 1024 * 512 * 2);
    short* vv   = (short*)alloc((size_t)16 * 512 * 1024 * 2);
    short* S    = (short*)alloc((size_t)16 * 1024 * 1024 * 2);
    short* h    = xnT;  // alias: xnT dead after qkv_gemm

    cvt_weights<<<1024, 256, 0, stream>>>(qkv_w, proj_w, wq, wp);
    gn_stats<<<512, 256, 0, stream>>>(x, mean, rstd);
    gn_apply_t<<<dim3(16, 8, 16), 256, 0, stream>>>(x, norm_w, norm_b, mean, rstd, xnT);
    qkv_gemm<<<dim3(4, 6, 16), 512, 0, stream>>>(wq, qkv_b, xnT, qT, kT, vv);
    s_gemm<<<dim3(4, 4, 16), 512, 0, stream>>>(kT, qT, S);
    softmax_rows<<<4096, 256, 0, stream>>>(S);
    pv_gemm<<<dim3(8, 2, 16), 512, 0, stream>>>(vv, S, h);
    proj_gemm<<<dim3(8, 2, 16), 512, 0, stream>>>(wp, proj_b, h, x, out);
}

// Round 5
// 240.027 us; speedup vs baseline: 1.0615x; 1.0127x over previous
//
#include <hip/hip_runtime.h>

#define GLD16(gp, lp) __builtin_amdgcn_global_load_lds( \
    (const __attribute__((address_space(1))) void*)(gp), \
    (__attribute__((address_space(3))) void*)(lp), 16, 0, 0)

typedef __attribute__((ext_vector_type(8))) short bf16x8;
typedef __attribute__((ext_vector_type(4))) float f32x4;

__device__ __forceinline__ short f2bf(float f) {
    union { float f; unsigned u; } x; x.f = f;
    unsigned r = x.u + 0x7fffu + ((x.u >> 16) & 1u);
    return (short)(r >> 16);
}
__device__ __forceinline__ float bf2f(short s) {
    union { unsigned u; float f; } x;
    x.u = ((unsigned)(unsigned short)s) << 16;
    return x.f;
}

// ---------------- K0: weights fp32->bf16  +  groupnorm stats (merged) ----------------
__global__ __launch_bounds__(256) void prep(
    const float* __restrict__ qkv_w, const float* __restrict__ proj_w,
    short* __restrict__ wq, short* __restrict__ wp,
    const float* __restrict__ x, float* __restrict__ mean, float* __restrict__ rstd)
{
    if (blockIdx.x < 1024) {
        int idx = blockIdx.x * 256 + threadIdx.x;   // 262144 float4s total
        const int NQ4 = (1536 * 512) / 4;           // 196608
        float4 f; short4 s;
        if (idx < NQ4) {
            f = ((const float4*)qkv_w)[idx];
            s.x = f2bf(f.x); s.y = f2bf(f.y); s.z = f2bf(f.z); s.w = f2bf(f.w);
            ((short4*)wq)[idx] = s;
        } else {
            int j = idx - NQ4;                      // 65536 for proj
            f = ((const float4*)proj_w)[j];
            s.x = f2bf(f.x); s.y = f2bf(f.y); s.z = f2bf(f.z); s.w = f2bf(f.w);
            ((short4*)wp)[j] = s;
        }
    } else {
        int bg = blockIdx.x - 1024;  // 0..511
        const float4* p = (const float4*)(x + (size_t)bg * 16384);
        float s = 0.f, ss = 0.f;
        for (int i = threadIdx.x; i < 4096; i += 256) {
            float4 v = p[i];
            s  += v.x + v.y + v.z + v.w;
            ss += v.x * v.x + v.y * v.y + v.z * v.z + v.w * v.w;
        }
        #pragma unroll
        for (int o = 32; o > 0; o >>= 1) {
            s  += __shfl_down(s, o);
            ss += __shfl_down(ss, o);
        }
        __shared__ float ls[4], lss[4];
        int wave = threadIdx.x >> 6;
        if ((threadIdx.x & 63) == 0) { ls[wave] = s; lss[wave] = ss; }
        __syncthreads();
        if (threadIdx.x == 0) {
            s  = ls[0] + ls[1] + ls[2] + ls[3];
            ss = lss[0] + lss[1] + lss[2] + lss[3];
            float m = s * (1.f / 16384.f);
            float var = ss * (1.f / 16384.f) - m * m;
            mean[bg] = m;
            rstd[bg] = rsqrtf(var + 1e-5f);
        }
    }
}

// ---------------- K2: normalize + transpose -> xnT [B,HW,C] bf16 ----------------
__global__ __launch_bounds__(256) void gn_apply_t(
    const float* __restrict__ x, const float* __restrict__ w, const float* __restrict__ bb,
    const float* __restrict__ mean, const float* __restrict__ rstd,
    short* __restrict__ xnT)
{
    __shared__ short tile[64][65];
    int b = blockIdx.z, cblk = blockIdx.y, nblk = blockIdx.x;
    int t = threadIdx.x;
    int nl = t & 63;
    int cb = t >> 6;  // 0..3
    #pragma unroll
    for (int i = 0; i < 16; ++i) {
        int cl = cb * 16 + i;
        int cg = cblk * 64 + cl;
        int bgid = b * 32 + (cg >> 4);
        float sc = rstd[bgid] * w[cg];
        float sh = bb[cg] - mean[bgid] * sc;
        float xv = x[((size_t)(b * 512 + cg)) * 1024 + nblk * 64 + nl];
        tile[cl][nl] = f2bf(xv * sc + sh);
    }
    __syncthreads();
    int ng = t >> 4;            // 0..15
    int c4 = (t & 15) * 4;
    #pragma unroll
    for (int p = 0; p < 4; ++p) {
        int nl2 = p * 16 + ng;
        short4 sv;
        sv.x = tile[c4 + 0][nl2];
        sv.y = tile[c4 + 1][nl2];
        sv.z = tile[c4 + 2][nl2];
        sv.w = tile[c4 + 3][nl2];
        *(short4*)&xnT[((size_t)(b * 1024 + nblk * 64 + nl2)) * 512 + cblk * 64 + c4] = sv;
    }
}

// ======== 128x128 NT-GEMM core: BK=32, 4 waves, 2-deep ring, 32 KiB LDS ========
// 4 blocks/CU co-resident (the m97/m114 recipe): cross-block wave overlap hides
// the per-tile barrier/latency chain. Swizzle (slot ^= (row>>1)&3) applied on
// BOTH pre-swizzled global source (linear gload_lds dest) and ds_read addrs.
// Schedule per iter: [stage(t+1)->other buf; ds_read(t); MFMA; vmcnt(0); barrier]
//  - stage(t+1) buffer's tile t-1 reads retired before previous barrier (safe)
//  - vmcnt(0)+barrier orders stage writes before next iter's reads (safe)
template<int NT>
__device__ __forceinline__ void gemm128(
    const short* __restrict__ A, const short* __restrict__ B,
    const int lda, const int ldb, short* lds, f32x4 acc[4][4])
{
    const int tid  = threadIdx.x;     // 0..255
    const int lane = tid & 63;
    const int wave = tid >> 6;        // 0..3
    const int wm = wave >> 1;
    const int wn = wave & 1;
    const int fr = lane & 15;
    const int fk = lane >> 4;         // 0..3

    const short* pa[2]; const short* pb[2]; int la[2], lb[2];
    #pragma unroll
    for (int i = 0; i < 2; ++i) {
        int cid = i * 256 + tid;       // 0..511 -> 128 rows x 4 slots
        int row = cid >> 2, sl = cid & 3;
        int csw = sl ^ ((row >> 1) & 3);   // pre-swizzled 16B slot
        pa[i] = A + (size_t)row * lda + csw * 8;
        pb[i] = B + (size_t)row * ldb + csw * 8;
        la[i] = cid * 8;               // linear LDS dest (shorts)
        lb[i] = 4096 + cid * 8;
    }
    auto stage = [&](int t) {
        const int base = (t & 1) * 8192;
        const int koff = t * 32;
        #pragma unroll
        for (int i = 0; i < 2; ++i) GLD16(pa[i] + koff, lds + base + la[i]);
        #pragma unroll
        for (int i = 0; i < 2; ++i) GLD16(pb[i] + koff, lds + base + lb[i]);
    };

    stage(0);
    asm volatile("s_waitcnt vmcnt(0)" ::: "memory");
    asm volatile("s_barrier" ::: "memory");

    const int arow0 = wm * 64 + fr;
    const int brow0 = wn * 64 + fr;

    for (int t = 0; t < NT; ++t) {
        const int base = (t & 1) * 8192;
        if (t + 1 < NT) stage(t + 1);     // into other buffer, ~full phase of lead
        bf16x8 af[4], bfr[4];
        #pragma unroll
        for (int m = 0; m < 4; ++m) {
            int R = arow0 + m * 16;
            af[m] = *(const bf16x8*)&lds[base + R * 32 + ((fk ^ ((R >> 1) & 3)) << 3)];
        }
        #pragma unroll
        for (int n = 0; n < 4; ++n) {
            int R = brow0 + n * 16;
            bfr[n] = *(const bf16x8*)&lds[base + 4096 + R * 32 + ((fk ^ ((R >> 1) & 3)) << 3)];
        }
        __builtin_amdgcn_s_setprio(1);
        #pragma unroll
        for (int m = 0; m < 4; ++m)
            #pragma unroll
            for (int n = 0; n < 4; ++n)
                acc[m][n] = __builtin_amdgcn_mfma_f32_16x16x32_bf16(af[m], bfr[n], acc[m][n], 0, 0, 0);
        __builtin_amdgcn_s_setprio(0);
        asm volatile("s_waitcnt vmcnt(0)" ::: "memory");
        asm volatile("s_barrier" ::: "memory");
    }
}

#define EPI_IDX() \
    const int lane = threadIdx.x & 63; \
    const int wave = threadIdx.x >> 6; \
    const int wm = (wave >> 1) * 64; \
    const int wn = (wave & 1) * 64; \
    const int fr = lane & 15; \
    const int fk = lane >> 4;

// ---------------- K3: QKV GEMM ----------------
__global__ __launch_bounds__(256, 4) void qkv_gemm(
    const short* __restrict__ wq, const float* __restrict__ qkv_b,
    const short* __restrict__ xnT,
    short* __restrict__ qT, short* __restrict__ kT, short* __restrict__ vv)
{
    __shared__ short lds[16384];
    const int b = blockIdx.z, bm = blockIdx.y, bn = blockIdx.x;
    const short* A  = wq + (size_t)bm * 128 * 512;
    const short* Bb = xnT + ((size_t)b * 1024 + bn * 128) * 512;
    f32x4 acc[4][4];
    #pragma unroll
    for (int m = 0; m < 4; ++m)
        #pragma unroll
        for (int n = 0; n < 4; ++n) acc[m][n] = (f32x4){0.f, 0.f, 0.f, 0.f};
    gemm128<16>(A, Bb, 512, 512, lds, acc);

    EPI_IDX();
    const int region = bm >> 2;  // 0=q 1=k 2=v
    const float qscale = 0.04419417382415922f;  // 1/sqrt(512)

    #pragma unroll
    for (int m = 0; m < 4; ++m) {
        int o0 = bm * 128 + wm + m * 16 + fk * 4;
        float4 bias = *(const float4*)&qkv_b[o0];
        float bb4[4] = {bias.x, bias.y, bias.z, bias.w};
        #pragma unroll
        for (int n = 0; n < 4; ++n) {
            int col = bn * 128 + wn + n * 16 + fr;
            f32x4 a = acc[m][n];
            if (region == 0) {
                short4 sv;
                sv.x = f2bf((a[0] + bb4[0]) * qscale);
                sv.y = f2bf((a[1] + bb4[1]) * qscale);
                sv.z = f2bf((a[2] + bb4[2]) * qscale);
                sv.w = f2bf((a[3] + bb4[3]) * qscale);
                *(short4*)&qT[((size_t)(b * 1024 + col)) * 512 + o0] = sv;
            } else if (region == 1) {
                short4 sv;
                sv.x = f2bf(a[0] + bb4[0]);
                sv.y = f2bf(a[1] + bb4[1]);
                sv.z = f2bf(a[2] + bb4[2]);
                sv.w = f2bf(a[3] + bb4[3]);
                *(short4*)&kT[((size_t)(b * 1024 + col)) * 512 + (o0 - 512)] = sv;
            } else {
                #pragma unroll
                for (int r = 0; r < 4; ++r)
                    vv[((size_t)(b * 512 + (o0 - 1024 + r))) * 1024 + col] = f2bf(a[r] + bb4[r]);
            }
        }
    }
}

// ---------------- K4: S = q.kT -> S[b,n,m] bf16 ----------------
__global__ __launch_bounds__(256, 4) void s_gemm(
    const short* __restrict__ kT, const short* __restrict__ qT, short* __restrict__ S)
{
    __shared__ short lds[16384];
    const int b = blockIdx.z, bm = blockIdx.y, bn = blockIdx.x;
    const short* A  = kT + ((size_t)b * 1024 + bm * 128) * 512;
    const short* Bb = qT + ((size_t)b * 1024 + bn * 128) * 512;
    f32x4 acc[4][4];
    #pragma unroll
    for (int m = 0; m < 4; ++m)
        #pragma unroll
        for (int n = 0; n < 4; ++n) acc[m][n] = (f32x4){0.f, 0.f, 0.f, 0.f};
    gemm128<16>(A, Bb, 512, 512, lds, acc);

    EPI_IDX();
    #pragma unroll
    for (int m = 0; m < 4; ++m) {
        int m0 = bm * 128 + wm + m * 16 + fk * 4;
        #pragma unroll
        for (int n = 0; n < 4; ++n) {
            int ncol = bn * 128 + wn + n * 16 + fr;
            f32x4 a = acc[m][n];
            short4 sv;
            sv.x = f2bf(a[0]); sv.y = f2bf(a[1]); sv.z = f2bf(a[2]); sv.w = f2bf(a[3]);
            *(short4*)&S[((size_t)(b * 1024 + ncol)) * 1024 + m0] = sv;
        }
    }
}

// ---------------- K5: row softmax in place on S (bf16) ----------------
__global__ __launch_bounds__(256) void softmax_rows(short* __restrict__ S)
{
    const int wave = threadIdx.x >> 6;
    const int lane = threadIdx.x & 63;
    size_t row = (size_t)blockIdx.x * 4 + wave;  // 16384 rows
    short* p = S + row * 1024;
    short4 raw[4];
    float v[16];
    #pragma unroll
    for (int i = 0; i < 4; ++i) raw[i] = ((short4*)p)[lane + 64 * i];
    #pragma unroll
    for (int i = 0; i < 4; ++i) {
        v[i * 4 + 0] = bf2f(raw[i].x);
        v[i * 4 + 1] = bf2f(raw[i].y);
        v[i * 4 + 2] = bf2f(raw[i].z);
        v[i * 4 + 3] = bf2f(raw[i].w);
    }
    float mx = v[0];
    #pragma unroll
    for (int i = 1; i < 16; ++i) mx = fmaxf(mx, v[i]);
    #pragma unroll
    for (int o = 1; o < 64; o <<= 1) mx = fmaxf(mx, __shfl_xor(mx, o));
    float sum = 0.f;
    #pragma unroll
    for (int i = 0; i < 16; ++i) { v[i] = __expf(v[i] - mx); sum += v[i]; }
    #pragma unroll
    for (int o = 1; o < 64; o <<= 1) sum += __shfl_xor(sum, o);
    float inv = 1.f / sum;
    #pragma unroll
    for (int i = 0; i < 4; ++i) {
        short4 sv;
        sv.x = f2bf(v[i * 4 + 0] * inv);
        sv.y = f2bf(v[i * 4 + 1] * inv);
        sv.z = f2bf(v[i * 4 + 2] * inv);
        sv.w = f2bf(v[i * 4 + 3] * inv);
        ((short4*)p)[lane + 64 * i] = sv;
    }
}

// ---------------- K6: h = P.v (A=v rows c, B=P rows n, K=1024) ----------------
__global__ __launch_bounds__(256, 4) void pv_gemm(
    const short* __restrict__ vv, const short* __restrict__ P, short* __restrict__ h)
{
    __shared__ short lds[16384];
    const int b = blockIdx.z, bm = blockIdx.y, bn = blockIdx.x;
    const short* A  = vv + ((size_t)b * 512 + bm * 128) * 1024;
    const short* Bb = P + ((size_t)b * 1024 + bn * 128) * 1024;
    f32x4 acc[4][4];
    #pragma unroll
    for (int m = 0; m < 4; ++m)
        #pragma unroll
        for (int n = 0; n < 4; ++n) acc[m][n] = (f32x4){0.f, 0.f, 0.f, 0.f};
    gemm128<32>(A, Bb, 1024, 1024, lds, acc);

    EPI_IDX();
    #pragma unroll
    for (int m = 0; m < 4; ++m) {
        int c0 = bm * 128 + wm + m * 16 + fk * 4;
        #pragma unroll
        for (int n = 0; n < 4; ++n) {
            int ncol = bn * 128 + wn + n * 16 + fr;
            f32x4 a = acc[m][n];
            short4 sv;
            sv.x = f2bf(a[0]); sv.y = f2bf(a[1]); sv.z = f2bf(a[2]); sv.w = f2bf(a[3]);
            *(short4*)&h[((size_t)(b * 1024 + ncol)) * 512 + c0] = sv;
        }
    }
}

// ---------------- K7: out = proj_w.h + proj_b + x ----------------
__global__ __launch_bounds__(256, 4) void proj_gemm(
    const short* __restrict__ wp, const float* __restrict__ proj_b,
    const short* __restrict__ h, const float* __restrict__ x, float* __restrict__ out)
{
    __shared__ short lds[16384];
    const int b = blockIdx.z, bm = blockIdx.y, bn = blockIdx.x;
    const short* A  = wp + (size_t)bm * 128 * 512;
    const short* Bb = h + ((size_t)b * 1024 + bn * 128) * 512;
    f32x4 acc[4][4];
    #pragma unroll
    for (int m = 0; m < 4; ++m)
        #pragma unroll
        for (int n = 0; n < 4; ++n) acc[m][n] = (f32x4){0.f, 0.f, 0.f, 0.f};
    gemm128<16>(A, Bb, 512, 512, lds, acc);

    EPI_IDX();
    #pragma unroll
    for (int m = 0; m < 4; ++m) {
        int o0 = bm * 128 + wm + m * 16 + fk * 4;
        float4 pb = *(const float4*)&proj_b[o0];
        float pb4[4] = {pb.x, pb.y, pb.z, pb.w};
        #pragma unroll
        for (int n = 0; n < 4; ++n) {
            int col = bn * 128 + wn + n * 16 + fr;
            f32x4 a = acc[m][n];
            #pragma unroll
            for (int r = 0; r < 4; ++r) {
                size_t idx = ((size_t)(b * 512 + o0 + r)) * 1024 + col;
                out[idx] = a[r] + pb4[r] + x[idx];
            }
        }
    }
}

extern "C" void kernel_launch(void* const* d_in, const int* in_sizes, int n_in,
                              void* d_out, int out_size, void* d_ws, size_t ws_size,
                              hipStream_t stream) {
    const float* x      = (const float*)d_in[0];
    const float* norm_w = (const float*)d_in[1];
    const float* norm_b = (const float*)d_in[2];
    const float* qkv_w  = (const float*)d_in[3];
    const float* qkv_b  = (const float*)d_in[4];
    const float* proj_w = (const float*)d_in[5];
    const float* proj_b = (const float*)d_in[6];
    float* out = (float*)d_out;

    char* ws = (char*)d_ws;
    size_t off = 0;
    auto alloc = [&](size_t bytes) {
        void* p = ws + off;
        off = (off + bytes + 255) & ~(size_t)255;
        return p;
    };
    float* mean = (float*)alloc(512 * 4);
    float* rstd = (float*)alloc(512 * 4);
    short* wq   = (short*)alloc((size_t)1536 * 512 * 2);
    short* wp   = (short*)alloc((size_t)512 * 512 * 2);
    short* xnT  = (short*)alloc((size_t)16 * 1024 * 512 * 2);
    short* qT   = (short*)alloc((size_t)16 * 1024 * 512 * 2);
    short* kT   = (short*)alloc((size_t)16 * 1024 * 512 * 2);
    short* vv   = (short*)alloc((size_t)16 * 512 * 1024 * 2);
    short* S    = (short*)alloc((size_t)16 * 1024 * 1024 * 2);
    short* h    = xnT;  // alias: xnT dead after qkv_gemm

    prep<<<1536, 256, 0, stream>>>(qkv_w, proj_w, wq, wp, x, mean, rstd);
    gn_apply_t<<<dim3(16, 8, 16), 256, 0, stream>>>(x, norm_w, norm_b, mean, rstd, xnT);
    qkv_gemm<<<dim3(8, 12, 16), 256, 0, stream>>>(wq, qkv_b, xnT, qT, kT, vv);
    s_gemm<<<dim3(8, 8, 16), 256, 0, stream>>>(kT, qT, S);
    softmax_rows<<<4096, 256, 0, stream>>>(S);
    pv_gemm<<<dim3(8, 4, 16), 256, 0, stream>>>(vv, S, h);
    proj_gemm<<<dim3(8, 4, 16), 256, 0, stream>>>(wp, proj_b, h, x, out);
}